// Round 5
// baseline (238.800 us; speedup 1.0000x reference)
//
#include <hip/hip_runtime.h>

#define B_ 8
#define S_ 32
#define C_ 3
#define H_ 256
#define W_ 256
#define HW_ (H_*W_)
#define CHW_ (C_*H_*W_)
#define NT_ 24            // K-tiles of 32
#define TILE_ELEMS 8192   // 256 rows x 32 k (B tiles in global)

typedef __attribute__((ext_vector_type(8))) short bf16x8;
typedef __attribute__((ext_vector_type(4))) float f32x4;
typedef unsigned int u32;
typedef u32 __attribute__((address_space(3)))* lds_u32p;
typedef const u32 __attribute__((address_space(1)))* glb_u32p;

// truncation-based hi/lo bf16 split of two floats, packed (x low half, y high)
__device__ __forceinline__ void split2(float x, float y, unsigned &hp, unsigned &lp) {
  unsigned ux = __float_as_uint(x), uy = __float_as_uint(y);
  unsigned hx = ux & 0xFFFF0000u, hy = uy & 0xFFFF0000u;
  float lx = x - __uint_as_float(hx);
  float ly = y - __uint_as_float(hy);
  hp = (ux >> 16) | hy;
  lp = (__float_as_uint(lx) >> 16) | (__float_as_uint(ly) & 0xFFFF0000u);
}

__device__ __forceinline__ void gl2lds16(const ushort* g, ushort* l) {
  __builtin_amdgcn_global_load_lds((glb_u32p)g, (lds_u32p)l, 16, 0, 0);
}

// -------- zero the global corr accumulator --------
__global__ void ct_zero(float* __restrict__ corrG) {
  int i = blockIdx.x * 256 + threadIdx.x;
  *(float4*)(corrG + i * 4) = make_float4(0.f, 0.f, 0.f, 0.f);
}

// -------- target row reciprocal norms (one wave per 768-elem row) --------
__global__ void ct_ntg(const float* __restrict__ target, float* __restrict__ rntg) {
  int r = (int)((blockIdx.x * (size_t)blockDim.x + threadIdx.x) >> 6);  // 0..2047
  int lane = threadIdx.x & 63;
  const float* base = target + (size_t)(r >> 8) * CHW_ + (size_t)(r & 255) * W_;
  float ss = 0.f;
#pragma unroll
  for (int c = 0; c < C_; ++c)
#pragma unroll
    for (int tt = 0; tt < W_/64; ++tt) {
      float v = base[c*HW_ + tt*64 + lane];
      ss = fmaf(v, v, ss);
    }
#pragma unroll
  for (int off = 32; off; off >>= 1) ss += __shfl_xor(ss, off);
  if (lane == 0) rntg[r] = 1.0f / fmaxf(sqrtf(ss), 1e-12f);
}

// -------- target -> bf16 hi/lo, per-(b,ktile) fragment layout (panel-contiguous) --------
__global__ void ct_bsplit(const float* __restrict__ target,
                          ushort* __restrict__ BhG, ushort* __restrict__ BlG) {
  int bx = blockIdx.x;             // b*24 + kt
  int b  = bx / 24, kt = bx % 24;
  int c  = kt >> 3, w0 = (kt & 7) * 32;
  int t  = threadIdx.x;
  int trow = t >> 3, tw = t & 7;   // 8 threads per row, 4 floats each
  const float* base = target + (size_t)(b*C_ + c) * HW_ + w0 + tw*4;
  ushort* oh = BhG + (size_t)bx * TILE_ELEMS;
  ushort* ol = BlG + (size_t)bx * TILE_ELEMS;
#pragma unroll
  for (int i = 0; i < 8; ++i) {
    int row = trow + 32*i;
    float4 v = *(const float4*)(base + (size_t)row * W_);
    unsigned h0, l0, h1, l1;
    split2(v.x, v.y, h0, l0); split2(v.z, v.w, h1, l1);
    int idx = (row>>4)*512 + (tw>>1)*128 + (row&15)*8 + (tw&1)*4;
    *(uint2*)&oh[idx] = make_uint2(h0, h1);
    *(uint2*)&ol[idx] = make_uint2(l0, l1);
  }
}

// -------- fused corr: 64x256 M-split MFMA GEMM + triangle skip + A-norms + partial diag --------
// grid = bs(256) x mb(4). Block rows [64mb,64mb+64), wave w computes col panel cp=mb+w (if <4).
__global__ __launch_bounds__(256, 3)
void ct_corr_mfma(const float* __restrict__ input,
                  const ushort* __restrict__ BhG, const ushort* __restrict__ BlG,
                  const float* __restrict__ rntg_g,
                  float* __restrict__ corrG) {
  __shared__ ushort AhL[2048], AlL[2048];     // 64 rows x 32 k, frag layout (8 KB)
  __shared__ ushort BhL[8192], BlL[8192];     // 256 rows x 32 k, frag layout (32 KB)
  __shared__ float ninSq[64], rnin[64], corrS[256];

  const int bx = blockIdx.x;
  const int bs = bx >> 2;          // b*S + s
  const int mb = bx & 3;           // row quarter
  const int bG = bs >> 5;
  const int t  = threadIdx.x;      // 0..255
  const int lane = t & 63;
  const int wid  = t >> 6;         // 0..3
  const int cp   = mb + wid;       // col panel (64 cols); active iff cp < 4
  const bool act = (cp < 4);

  const float* Abase = input + (size_t)bs * CHW_ + (size_t)(mb * 64) * W_;

  if (t < 64) ninSq[t] = 0.f;
  corrS[t] = 0.f;

  f32x4 acc[4][4];
#pragma unroll
  for (int m = 0; m < 4; ++m)
#pragma unroll
    for (int n = 0; n < 4; ++n) acc[m][n] = (f32x4){0.f, 0.f, 0.f, 0.f};

  float4 pa[2];
  float ssA[2] = {0.f, 0.f};

  // A-row/k mapping for this thread (static across tiles): f = p*256 + t
  // row = f>>3 (0..63), kk = (f&7)*4; LDS idx = (row>>4)*512 + (kk>>3)*128 + (row&15)*8 + (kk&7)
#define ISSUE_A(KT) {                                                         \
    const float* Ab = Abase + (size_t)((KT) >> 3) * HW_ + ((KT) & 7) * 32;    \
    _Pragma("unroll")                                                         \
    for (int p = 0; p < 2; ++p) {                                             \
      int f = p*256 + t;                                                      \
      pa[p] = *(const float4*)(Ab + (size_t)(f >> 3) * W_ + (f & 7) * 4);     \
    } }

#define STASH_A() {                                                           \
    _Pragma("unroll")                                                         \
    for (int p = 0; p < 2; ++p) {                                             \
      int f = p*256 + t;                                                      \
      int row = f >> 3, kk = (f & 7) * 4;                                     \
      int idx = (row>>4)*512 + (kk>>3)*128 + (row&15)*8 + (kk&4);             \
      float4 va = pa[p];                                                      \
      ssA[p] = fmaf(va.x, va.x, fmaf(va.y, va.y,                              \
               fmaf(va.z, va.z, fmaf(va.w, va.w, ssA[p]))));                  \
      unsigned h0, l0, h1, l1;                                                \
      split2(va.x, va.y, h0, l0); split2(va.z, va.w, h1, l1);                 \
      *(uint2*)&AhL[idx] = make_uint2(h0, h1);                                \
      *(uint2*)&AlL[idx] = make_uint2(l0, l1);                                \
    } }

  // wave DMA-loads ONLY its own panel's B chunk (8 KB hi+lo): own-vmcnt covered
#define ISSUE_B(KT) if (act) {                                                \
    const ushort* gh = BhG + (size_t)(bG*NT_ + (KT)) * TILE_ELEMS + cp*2048;  \
    const ushort* gl = BlG + (size_t)(bG*NT_ + (KT)) * TILE_ELEMS + cp*2048;  \
    _Pragma("unroll")                                                         \
    for (int o = 0; o < 4; ++o)                                               \
      gl2lds16(gh + o*512 + lane*8, &BhL[cp*2048 + o*512]);                   \
    _Pragma("unroll")                                                         \
    for (int o = 0; o < 4; ++o)                                               \
      gl2lds16(gl + o*512 + lane*8, &BlL[cp*2048 + o*512]);                   \
  }

#define SBAR0() __builtin_amdgcn_sched_barrier(0)

  ISSUE_A(0);
  SBAR0();

  for (int kt = 0; kt < NT_; ++kt) {
    // barrier 1: everyone done reading LDS of previous tile
    SBAR0();
    __builtin_amdgcn_s_barrier();
    SBAR0();
    ISSUE_B(kt);                 // 8 DMA loads (active waves)
    SBAR0();
    STASH_A();                   // compiler auto-waits A regs (vmcnt(8)), B DMA keeps flying
    SBAR0();
    if (kt < NT_ - 1) { ISSUE_A(kt + 1); }
    SBAR0();
    // staging done: ds_writes flushed; B DMA drained, next A (2 loads) still in flight
    asm volatile("s_waitcnt lgkmcnt(0)" ::: "memory");
    if (kt < NT_ - 1) { asm volatile("s_waitcnt vmcnt(2)" ::: "memory"); }
    else              { asm volatile("s_waitcnt vmcnt(0)" ::: "memory"); }
    SBAR0();
    __builtin_amdgcn_s_barrier();
    SBAR0();

    if (act) {
      bf16x8 bh[4], bl[4];
#pragma unroll
      for (int n = 0; n < 4; ++n) {
        int ct = cp*4 + n;
        bh[n] = *(const bf16x8*)&BhL[ct*512 + lane*8];
        bl[n] = *(const bf16x8*)&BlL[ct*512 + lane*8];
      }
      __builtin_amdgcn_s_setprio(1);
#pragma unroll
      for (int m = 0; m < 4; ++m) {
        bf16x8 ah = *(const bf16x8*)&AhL[m*512 + lane*8];
        bf16x8 al = *(const bf16x8*)&AlL[m*512 + lane*8];
#pragma unroll
        for (int n = 0; n < 4; ++n) {
          acc[m][n] = __builtin_amdgcn_mfma_f32_16x16x32_bf16(ah, bh[n], acc[m][n], 0, 0, 0);
          acc[m][n] = __builtin_amdgcn_mfma_f32_16x16x32_bf16(ah, bl[n], acc[m][n], 0, 0, 0);
          acc[m][n] = __builtin_amdgcn_mfma_f32_16x16x32_bf16(al, bh[n], acc[m][n], 0, 0, 0);
        }
      }
      __builtin_amdgcn_s_setprio(0);
    }
  }

  // fused A-norms (all threads staged 2 fixed rows)
#pragma unroll
  for (int p = 0; p < 2; ++p) {
    int row = (p*256 + t) >> 3;
    atomicAdd(&ninSq[row], ssA[p]);
  }
  __syncthreads();
  if (t < 64) rnin[t] = 1.0f / fmaxf(sqrtf(ninSq[t]), 1e-12f);
  __syncthreads();

  // normalize + reduce upper diagonals into LDS (q = col - row >= 0)
  if (act) {
#pragma unroll
    for (int n = 0; n < 4; ++n) {
      int col = cp*64 + n*16 + (lane & 15);
      float rc = rntg_g[bG*256 + col];
#pragma unroll
      for (int m = 0; m < 4; ++m) {
        f32x4 a = acc[m][n];
#pragma unroll
        for (int r = 0; r < 4; ++r) {
          int lrow = m*16 + (lane >> 4)*4 + r;
          int q = col - (mb*64 + lrow);
          if (q >= 0) atomicAdd(&corrS[q], a[r] * rnin[lrow] * rc);
        }
      }
    }
  }
  __syncthreads();

  // one global atomic per q per block
  atomicAdd(&corrG[bs*256 + t], corrS[t]);
}

// -------- argmax over p (first max = smallest p wins) -> shift --------
__global__ void ct_argmax(const float* __restrict__ corrG, int* __restrict__ shift) {
  int bs = blockIdx.x;
  int lane = threadIdx.x;          // 0..63
  unsigned long long key = 0;
#pragma unroll
  for (int i = 0; i < 4; ++i) {
    int q = lane + 64*i;
    float v = corrG[bs*256 + q] / (float)(256 - q);   // mean over overlap p+1 = 256-q
    unsigned u = __float_as_uint(v);
    u = (u & 0x80000000u) ? ~u : (u | 0x80000000u);
    unsigned long long k = ((unsigned long long)u << 32) | (unsigned)q;
    if (k > key) key = k;
  }
#pragma unroll
  for (int off = 32; off; off >>= 1) {
    unsigned long long o = __shfl_xor(key, off);
    if (o > key) key = o;
  }
  if (lane == 0) shift[bs] = (int)(key & 0xFFFFFFFFull);
}

// -------- shifted gather --------
__global__ void ct_gather(const float* __restrict__ input,
                          const int* __restrict__ shift,
                          float* __restrict__ out) {
  size_t idx = (size_t)blockIdx.x * blockDim.x + threadIdx.x;  // float4 units
  int w4 = (int)(idx & 63);
  int h  = (int)((idx >> 6) & 255);
  int sc = (int)(idx >> 14);
  int bs = sc / 3;
  int hh = h + shift[bs];
  float4 v = make_float4(0.f, 0.f, 0.f, 0.f);
  if (hh < H_) v = *(const float4*)(input + ((size_t)sc << 16) + (size_t)hh * W_ + w4*4);
  *(float4*)(out + (idx << 2)) = v;
}

extern "C" void kernel_launch(void* const* d_in, const int* in_sizes, int n_in,
                              void* d_out, int out_size, void* d_ws, size_t ws_size,
                              hipStream_t stream) {
  const float* input  = (const float*)d_in[0];
  const float* target = (const float*)d_in[1];
  float* out = (float*)d_out;

  float* rntg  = (float*)d_ws;                      // 2048 f
  float* corrG = rntg + 2048;                       // 65536 f
  int*   shift = (int*)(corrG + 65536);             // 256 i
  ushort* BhG  = (ushort*)(shift + 256);            // 8*24*8192 ushort = 3 MB
  ushort* BlG  = BhG + (size_t)B_ * NT_ * TILE_ELEMS;

  ct_zero      <<<64, 256, 0, stream>>>(corrG);
  ct_ntg       <<<512, 256, 0, stream>>>(target, rntg);
  ct_bsplit    <<<B_ * NT_, 256, 0, stream>>>(target, BhG, BlG);
  ct_corr_mfma <<<B_ * S_ * 4, 256, 0, stream>>>(input, BhG, BlG, rntg, corrG);
  ct_argmax    <<<B_ * S_, 64, 0, stream>>>(corrG, shift);
  ct_gather    <<<(B_*S_*C_*H_*W_/4) / 256, 256, 0, stream>>>(input, shift, out);
}

// Round 6
// 204.047 us; speedup vs baseline: 1.1703x; 1.1703x over previous
//
#include <hip/hip_runtime.h>

#define B_ 8
#define S_ 32
#define C_ 3
#define H_ 256
#define W_ 256
#define HW_ (H_*W_)
#define CHW_ (C_*H_*W_)
#define NT_ 24            // K-tiles of 32
#define TILE_ELEMS 8192   // 256 rows x 32 k (B tiles in global, frag layout)

typedef __attribute__((ext_vector_type(8))) short bf16x8;
typedef __attribute__((ext_vector_type(4))) float f32x4;

// truncation-based hi/lo bf16 split of two floats, packed (x low half, y high)
__device__ __forceinline__ void split2(float x, float y, unsigned &hp, unsigned &lp) {
  unsigned ux = __float_as_uint(x), uy = __float_as_uint(y);
  unsigned hx = ux & 0xFFFF0000u, hy = uy & 0xFFFF0000u;
  float lx = x - __uint_as_float(hx);
  float ly = y - __uint_as_float(hy);
  hp = (ux >> 16) | hy;
  lp = (__float_as_uint(lx) >> 16) | (__float_as_uint(ly) & 0xFFFF0000u);
}

// -------- zero the global corr accumulator --------
__global__ void ct_zero(float* __restrict__ corrG) {
  int i = blockIdx.x * 256 + threadIdx.x;
  *(float4*)(corrG + i * 4) = make_float4(0.f, 0.f, 0.f, 0.f);
}

// -------- target row reciprocal norms (one wave per 768-elem row) --------
__global__ void ct_ntg(const float* __restrict__ target, float* __restrict__ rntg) {
  int r = (int)((blockIdx.x * (size_t)blockDim.x + threadIdx.x) >> 6);  // 0..2047
  int lane = threadIdx.x & 63;
  const float* base = target + (size_t)(r >> 8) * CHW_ + (size_t)(r & 255) * W_;
  float ss = 0.f;
#pragma unroll
  for (int c = 0; c < C_; ++c)
#pragma unroll
    for (int tt = 0; tt < W_/64; ++tt) {
      float v = base[c*HW_ + tt*64 + lane];
      ss = fmaf(v, v, ss);
    }
#pragma unroll
  for (int off = 32; off; off >>= 1) ss += __shfl_xor(ss, off);
  if (lane == 0) rntg[r] = 1.0f / fmaxf(sqrtf(ss), 1e-12f);
}

// -------- target -> bf16 hi/lo, per-(b,ktile) fragment layout --------
__global__ void ct_bsplit(const float* __restrict__ target,
                          ushort* __restrict__ BhG, ushort* __restrict__ BlG) {
  int bx = blockIdx.x;             // b*24 + kt
  int b  = bx / 24, kt = bx % 24;
  int c  = kt >> 3, w0 = (kt & 7) * 32;
  int t  = threadIdx.x;
  int trow = t >> 3, tw = t & 7;   // 8 threads per row, 4 floats each
  const float* base = target + (size_t)(b*C_ + c) * HW_ + w0 + tw*4;
  ushort* oh = BhG + (size_t)bx * TILE_ELEMS;
  ushort* ol = BlG + (size_t)bx * TILE_ELEMS;
#pragma unroll
  for (int i = 0; i < 8; ++i) {
    int row = trow + 32*i;
    float4 v = *(const float4*)(base + (size_t)row * W_);
    unsigned h0, l0, h1, l1;
    split2(v.x, v.y, h0, l0); split2(v.z, v.w, h1, l1);
    int idx = (row>>4)*512 + (tw>>1)*128 + (row&15)*8 + (tw&1)*4;
    *(uint2*)&oh[idx] = make_uint2(h0, h1);
    *(uint2*)&ol[idx] = make_uint2(l0, l1);
  }
}

// -------- fused corr: 128x128 triangle-decomposed MFMA GEMM + local norms + diag --------
// grid = bs(256) x part(3): part0=(r0,c0), part1=(r0,c1), part2=(r1,c1).
// 8 waves, wave tile 32x64 (2x4 frags of 16x16x32), acc = 32 VGPR.
__global__ __launch_bounds__(512, 4)
void ct_corr_mfma(const float* __restrict__ input,
                  const ushort* __restrict__ BhG, const ushort* __restrict__ BlG,
                  const float* __restrict__ rntg_g,
                  float* __restrict__ corrG) {
  __shared__ ushort AhL[4096], AlL[4096];     // 128 rows x 32 k (8 KB each)
  __shared__ ushort BhL[4096], BlL[4096];     // 128 cols x 32 k (8 KB each)
  __shared__ float ninSq[128], rnin[128], corrS[256];

  const int bx = blockIdx.x;
  const int bs = bx / 3;           // b*S + s
  const int part = bx - bs*3;      // 0,1,2
  const int rbase = (part == 2) ? 128 : 0;
  const int cbase = (part == 0) ? 0 : 128;
  const int bG = bs >> 5;
  const int t  = threadIdx.x;      // 0..511
  const int lane = t & 63;
  const int wid  = t >> 6;         // 0..7
  const int wm   = wid >> 1;       // 0..3 : 32-row group
  const int wn   = wid & 1;        // 0..1 : 64-col group

  const float* Abase = input + (size_t)bs * CHW_ + (size_t)rbase * W_;
  const int panel_off = (cbase >> 4) * 512;   // offset of col-panel in B frag tile

  if (t < 128) ninSq[t] = 0.f;
  if (t < 256) corrS[t] = 0.f;

  f32x4 acc[2][4];
#pragma unroll
  for (int m = 0; m < 2; ++m)
#pragma unroll
    for (int n = 0; n < 4; ++n) acc[m][n] = (f32x4){0.f, 0.f, 0.f, 0.f};

  float4 pa[2];          // A: 128x32 f32 = 2 float4 / thread
  uint4 pbh, pbl;        // B: 128x32 bf16 hi+lo = 8+8 ushort / thread
  float ssA[2] = {0.f, 0.f};

#define ISSUE(KT) {                                                           \
    const float* Ab = Abase + (size_t)((KT) >> 3) * HW_ + ((KT) & 7) * 32;    \
    _Pragma("unroll")                                                         \
    for (int p = 0; p < 2; ++p) {                                             \
      int f = p*512 + t;                                                      \
      pa[p] = *(const float4*)(Ab + (size_t)(f >> 3) * W_ + (f & 7) * 4);     \
    }                                                                         \
    const ushort* gB = BhG + (size_t)(bG*NT_ + (KT)) * TILE_ELEMS + panel_off;\
    const ushort* gL = BlG + (size_t)(bG*NT_ + (KT)) * TILE_ELEMS + panel_off;\
    pbh = *(const uint4*)(gB + t*8);                                          \
    pbl = *(const uint4*)(gL + t*8); }

#define STASH() {                                                             \
    _Pragma("unroll")                                                         \
    for (int p = 0; p < 2; ++p) {                                             \
      int f = p*512 + t;                                                      \
      int row = f >> 3, kk = (f & 7) * 4;                                     \
      int idx = (row>>4)*512 + (kk>>3)*128 + (row&15)*8 + (kk&7);             \
      float4 va = pa[p];                                                      \
      ssA[p] = fmaf(va.x, va.x, fmaf(va.y, va.y,                              \
               fmaf(va.z, va.z, fmaf(va.w, va.w, ssA[p]))));                  \
      unsigned h0, l0, h1, l1;                                                \
      split2(va.x, va.y, h0, l0); split2(va.z, va.w, h1, l1);                 \
      *(uint2*)&AhL[idx] = make_uint2(h0, h1);                                \
      *(uint2*)&AlL[idx] = make_uint2(l0, l1);                                \
    }                                                                         \
    *(uint4*)&BhL[t*8] = pbh;                                                 \
    *(uint4*)&BlL[t*8] = pbl; }

  ISSUE(0);

  for (int kt = 0; kt < NT_; ++kt) {
    __syncthreads();               // LDS free (prev tile's reads done)
    STASH();
    __syncthreads();
    if (kt < NT_ - 1) ISSUE(kt + 1);   // prefetch under compute

    bf16x8 bh[4], bl[4];
#pragma unroll
    for (int n = 0; n < 4; ++n) {
      int ct = wn*4 + n;
      bh[n] = *(const bf16x8*)&BhL[ct*512 + lane*8];
      bl[n] = *(const bf16x8*)&BlL[ct*512 + lane*8];
    }
    __builtin_amdgcn_s_setprio(1);
#pragma unroll
    for (int m = 0; m < 2; ++m) {
      int rt = wm*2 + m;
      bf16x8 ah = *(const bf16x8*)&AhL[rt*512 + lane*8];
      bf16x8 al = *(const bf16x8*)&AlL[rt*512 + lane*8];
#pragma unroll
      for (int n = 0; n < 4; ++n) {
        acc[m][n] = __builtin_amdgcn_mfma_f32_16x16x32_bf16(ah, bh[n], acc[m][n], 0, 0, 0);
        acc[m][n] = __builtin_amdgcn_mfma_f32_16x16x32_bf16(ah, bl[n], acc[m][n], 0, 0, 0);
        acc[m][n] = __builtin_amdgcn_mfma_f32_16x16x32_bf16(al, bh[n], acc[m][n], 0, 0, 0);
      }
    }
    __builtin_amdgcn_s_setprio(0);
  }

  // local A-norms over this block's 128 rows (full K covered by this block)
#pragma unroll
  for (int p = 0; p < 2; ++p) {
    int row = (p*512 + t) >> 3;
    atomicAdd(&ninSq[row], ssA[p]);
  }
  __syncthreads();
  if (t < 128) rnin[t] = 1.0f / fmaxf(sqrtf(ninSq[t]), 1e-12f);
  __syncthreads();

  // normalize + reduce upper diagonals into LDS (q = col - row >= 0)
#pragma unroll
  for (int n = 0; n < 4; ++n) {
    int col = cbase + wn*64 + n*16 + (lane & 15);
    float rc = rntg_g[bG*256 + col];
#pragma unroll
    for (int m = 0; m < 2; ++m) {
      f32x4 a = acc[m][n];
#pragma unroll
      for (int r = 0; r < 4; ++r) {
        int lrow = wm*32 + m*16 + (lane >> 4)*4 + r;
        int q = col - (rbase + lrow);
        if (q >= 0) atomicAdd(&corrS[q], a[r] * rnin[lrow] * rc);
      }
    }
  }
  __syncthreads();

  // one global atomic per q per block
  if (t < 256) atomicAdd(&corrG[bs*256 + t], corrS[t]);
}

// -------- argmax over p (first max = smallest p wins) -> shift --------
__global__ void ct_argmax(const float* __restrict__ corrG, int* __restrict__ shift) {
  int bs = blockIdx.x;
  int lane = threadIdx.x;          // 0..63
  unsigned long long key = 0;
#pragma unroll
  for (int i = 0; i < 4; ++i) {
    int q = lane + 64*i;
    float v = corrG[bs*256 + q] / (float)(256 - q);   // mean over overlap p+1 = 256-q
    unsigned u = __float_as_uint(v);
    u = (u & 0x80000000u) ? ~u : (u | 0x80000000u);
    unsigned long long k = ((unsigned long long)u << 32) | (unsigned)q;
    if (k > key) key = k;
  }
#pragma unroll
  for (int off = 32; off; off >>= 1) {
    unsigned long long o = __shfl_xor(key, off);
    if (o > key) key = o;
  }
  if (lane == 0) shift[bs] = (int)(key & 0xFFFFFFFFull);
}

// -------- shifted gather --------
__global__ void ct_gather(const float* __restrict__ input,
                          const int* __restrict__ shift,
                          float* __restrict__ out) {
  size_t idx = (size_t)blockIdx.x * blockDim.x + threadIdx.x;  // float4 units
  int w4 = (int)(idx & 63);
  int h  = (int)((idx >> 6) & 255);
  int sc = (int)(idx >> 14);
  int bs = sc / 3;
  int hh = h + shift[bs];
  float4 v = make_float4(0.f, 0.f, 0.f, 0.f);
  if (hh < H_) v = *(const float4*)(input + ((size_t)sc << 16) + (size_t)hh * W_ + w4*4);
  *(float4*)(out + (idx << 2)) = v;
}

extern "C" void kernel_launch(void* const* d_in, const int* in_sizes, int n_in,
                              void* d_out, int out_size, void* d_ws, size_t ws_size,
                              hipStream_t stream) {
  const float* input  = (const float*)d_in[0];
  const float* target = (const float*)d_in[1];
  float* out = (float*)d_out;

  float* rntg  = (float*)d_ws;                      // 2048 f
  float* corrG = rntg + 2048;                       // 65536 f
  int*   shift = (int*)(corrG + 65536);             // 256 i
  ushort* BhG  = (ushort*)(shift + 256);            // 8*24*8192 ushort = 3 MB
  ushort* BlG  = BhG + (size_t)B_ * NT_ * TILE_ELEMS;

  ct_zero      <<<64, 256, 0, stream>>>(corrG);
  ct_ntg       <<<512, 256, 0, stream>>>(target, rntg);
  ct_bsplit    <<<B_ * NT_, 256, 0, stream>>>(target, BhG, BlG);
  ct_corr_mfma <<<B_ * S_ * 3, 512, 0, stream>>>(input, BhG, BlG, rntg, corrG);
  ct_argmax    <<<B_ * S_, 64, 0, stream>>>(corrG, shift);
  ct_gather    <<<(B_*S_*C_*H_*W_/4) / 256, 256, 0, stream>>>(input, shift, out);
}

// Round 7
// 187.942 us; speedup vs baseline: 1.2706x; 1.0857x over previous
//
#include <hip/hip_runtime.h>

#define B_ 8
#define S_ 32
#define C_ 3
#define H_ 256
#define W_ 256
#define HW_ (H_*W_)
#define CHW_ (C_*H_*W_)
#define NT_ 24            // 32-wide K-tiles (B global pre-split granularity)
#define NT64_ 12          // 64-wide K-tiles in the GEMM loop
#define TILE_ELEMS 8192   // 256 rows x 32 k per pre-split B tile

typedef __attribute__((ext_vector_type(8))) short bf16x8;
typedef __attribute__((ext_vector_type(4))) float f32x4;
typedef unsigned int u32;
typedef u32 __attribute__((address_space(3)))* lds_u32p;
typedef const u32 __attribute__((address_space(1)))* glb_u32p;

// truncation-based hi/lo bf16 split of two floats, packed (x low half, y high)
__device__ __forceinline__ void split2(float x, float y, unsigned &hp, unsigned &lp) {
  unsigned ux = __float_as_uint(x), uy = __float_as_uint(y);
  unsigned hx = ux & 0xFFFF0000u, hy = uy & 0xFFFF0000u;
  float lx = x - __uint_as_float(hx);
  float ly = y - __uint_as_float(hy);
  hp = (ux >> 16) | hy;
  lp = (__float_as_uint(lx) >> 16) | (__float_as_uint(ly) & 0xFFFF0000u);
}

__device__ __forceinline__ void gl2lds16(const ushort* g, ushort* l) {
  __builtin_amdgcn_global_load_lds((glb_u32p)g, (lds_u32p)l, 16, 0, 0);
}

// -------- target row reciprocal norms (one wave per 768-elem row) --------
__global__ void ct_ntg(const float* __restrict__ target, float* __restrict__ rntg) {
  int r = (int)((blockIdx.x * (size_t)blockDim.x + threadIdx.x) >> 6);  // 0..2047
  int lane = threadIdx.x & 63;
  const float* base = target + (size_t)(r >> 8) * CHW_ + (size_t)(r & 255) * W_;
  float ss = 0.f;
#pragma unroll
  for (int c = 0; c < C_; ++c)
#pragma unroll
    for (int tt = 0; tt < W_/64; ++tt) {
      float v = base[c*HW_ + tt*64 + lane];
      ss = fmaf(v, v, ss);
    }
#pragma unroll
  for (int off = 32; off; off >>= 1) ss += __shfl_xor(ss, off);
  if (lane == 0) rntg[r] = 1.0f / fmaxf(sqrtf(ss), 1e-12f);
}

// -------- target -> bf16 hi/lo, per-(b,ktile32) fragment layout --------
__global__ void ct_bsplit(const float* __restrict__ target,
                          ushort* __restrict__ BhG, ushort* __restrict__ BlG) {
  int bx = blockIdx.x;             // b*24 + kt
  int b  = bx / 24, kt = bx % 24;
  int c  = kt >> 3, w0 = (kt & 7) * 32;
  int t  = threadIdx.x;
  int trow = t >> 3, tw = t & 7;   // 8 threads per row, 4 floats each
  const float* base = target + (size_t)(b*C_ + c) * HW_ + w0 + tw*4;
  ushort* oh = BhG + (size_t)bx * TILE_ELEMS;
  ushort* ol = BlG + (size_t)bx * TILE_ELEMS;
#pragma unroll
  for (int i = 0; i < 8; ++i) {
    int row = trow + 32*i;
    float4 v = *(const float4*)(base + (size_t)row * W_);
    unsigned h0, l0, h1, l1;
    split2(v.x, v.y, h0, l0); split2(v.z, v.w, h1, l1);
    int idx = (row>>4)*512 + (tw>>1)*128 + (row&15)*8 + (tw&1)*4;
    *(uint2*)&oh[idx] = make_uint2(h0, h1);
    *(uint2*)&ol[idx] = make_uint2(l0, l1);
  }
}

// -------- fused corr: per-(b,s) 256x256 GEMM, K=768, BK=64, bf16 3-term split
//          + fused A-norms + diagonal reduce + argmax --------
// 8 waves, wave tile 128x64. LDS: A hi/lo + B hi/lo, 64 k deep = 128 KB, single-buffered.
// A: reg-staged (f32 load -> split -> ds_write, LDS ushort addr = 4*f, linear in t).
// B: per-wave own-panel global_load_lds DMA from pre-split global.
__global__ __launch_bounds__(512)
void ct_corr_mfma(const float* __restrict__ input,
                  const ushort* __restrict__ BhG, const ushort* __restrict__ BlG,
                  const float* __restrict__ rntg_g,
                  int* __restrict__ shift_out) {
  __shared__ ushort AhL[16384], AlL[16384], BhL[16384], BlL[16384];  // 128 KB
  __shared__ float ninSq[256], rnin[256], rntg_s[256], corrS[256];
  __shared__ unsigned long long wkey[4];

  const int bs = blockIdx.x;          // b*S + s
  const int bG = bs >> 5;
  const int t  = threadIdx.x;         // 0..511
  const int lane = t & 63;
  const int wid  = t >> 6;            // 0..7
  const int wm   = wid >> 2;          // 0..1 : M half (128 rows)
  const int wn   = wid & 3;           // 0..3 : N quarter (64 cols)

  const float* Abase = input + (size_t)bs * CHW_;

  if (t < 256) { ninSq[t] = 0.f; corrS[t] = 0.f; rntg_s[t] = rntg_g[bG*256 + t]; }

  f32x4 acc[8][4];
#pragma unroll
  for (int m = 0; m < 8; ++m)
#pragma unroll
    for (int n = 0; n < 4; ++n) acc[m][n] = (f32x4){0.f, 0.f, 0.f, 0.f};

  float4 pa[8];
  float ssA[8] = {0.f,0.f,0.f,0.f,0.f,0.f,0.f,0.f};

#define SBAR0() __builtin_amdgcn_sched_barrier(0)

  // bijection: LDS ushort addr = 4*f, f = p*512+t; kh=f>>11, f2=f&2047,
  // row=(f2>>7)*16+((f2>>1)&15), kk=((f2>>5)&3)*8+(f2&1)*4, k=kh*32+kk.
#define ISSUE_A(KT) {                                                         \
    const float* Ab = Abase + (size_t)((KT) >> 2) * HW_ + ((KT) & 3) * 64;    \
    _Pragma("unroll")                                                         \
    for (int p = 0; p < 8; ++p) {                                             \
      int f  = p*512 + t;                                                     \
      int kh = f >> 11, f2 = f & 2047;                                        \
      int row = (f2 >> 7)*16 + ((f2 >> 1) & 15);                              \
      int kk  = ((f2 >> 5) & 3)*8 + (f2 & 1)*4;                               \
      pa[p] = *(const float4*)(Ab + (size_t)row * W_ + kh*32 + kk);           \
    } }

#define STASH_A() {                                                           \
    _Pragma("unroll")                                                         \
    for (int p = 0; p < 8; ++p) {                                             \
      int f = p*512 + t;                                                      \
      float4 va = pa[p];                                                      \
      ssA[p] = fmaf(va.x, va.x, fmaf(va.y, va.y,                              \
               fmaf(va.z, va.z, fmaf(va.w, va.w, ssA[p]))));                  \
      unsigned h0, l0, h1, l1;                                                \
      split2(va.x, va.y, h0, l0); split2(va.z, va.w, h1, l1);                 \
      *(uint2*)&AhL[4*f] = make_uint2(h0, h1);                                \
      *(uint2*)&AlL[4*f] = make_uint2(l0, l1);                                \
    } }

  // wave DMA-loads its OWN col-panel (wn*64..) for both K-halves: 16 loads
#define ISSUE_B(KT) {                                                         \
    _Pragma("unroll")                                                         \
    for (int kh = 0; kh < 2; ++kh) {                                          \
      const ushort* gh = BhG + (size_t)(bG*NT_ + (KT)*2 + kh) * TILE_ELEMS + wn*2048; \
      const ushort* gl = BlG + (size_t)(bG*NT_ + (KT)*2 + kh) * TILE_ELEMS + wn*2048; \
      _Pragma("unroll")                                                       \
      for (int o = 0; o < 4; ++o)                                             \
        gl2lds16(gh + o*512 + lane*8, &BhL[kh*8192 + wn*2048 + o*512]);       \
      _Pragma("unroll")                                                       \
      for (int o = 0; o < 4; ++o)                                             \
        gl2lds16(gl + o*512 + lane*8, &BlL[kh*8192 + wn*2048 + o*512]);       \
    } }

  ISSUE_A(0);
  SBAR0();

  for (int kt = 0; kt < NT64_; ++kt) {
    // loop-top barrier: all waves done reading prev tile's LDS (regs consumed)
    SBAR0();
    __builtin_amdgcn_s_barrier();
    SBAR0();
    ISSUE_B(kt);                  // 16 DMA into vmcnt queue
    SBAR0();
    STASH_A();                    // compiler waits A(kt) regs; B DMA keeps flying
    SBAR0();
    if (kt < NT64_ - 1) { ISSUE_A(kt + 1); }   // queue = [B16, A8]
    SBAR0();
    asm volatile("s_waitcnt lgkmcnt(0)" ::: "memory");   // ds_writes flushed
    SBAR0();
    __builtin_amdgcn_s_barrier();
    SBAR0();
    if (kt < NT64_ - 1) { asm volatile("s_waitcnt vmcnt(8)" ::: "memory"); }
    else                { asm volatile("s_waitcnt vmcnt(0)" ::: "memory"); }
    SBAR0();

#pragma unroll
    for (int kh = 0; kh < 2; ++kh) {
      const int kb = kh * 8192;
      bf16x8 bh[4], bl[4];
#pragma unroll
      for (int n = 0; n < 4; ++n) {
        int ct = wn*4 + n;
        bh[n] = *(const bf16x8*)&BhL[kb + ct*512 + lane*8];
        bl[n] = *(const bf16x8*)&BlL[kb + ct*512 + lane*8];
      }
      __builtin_amdgcn_s_setprio(1);
#pragma unroll
      for (int m = 0; m < 8; ++m) {
        int rt = wm*8 + m;
        bf16x8 ah = *(const bf16x8*)&AhL[kb + rt*512 + lane*8];
        bf16x8 al = *(const bf16x8*)&AlL[kb + rt*512 + lane*8];
#pragma unroll
        for (int n = 0; n < 4; ++n) {
          acc[m][n] = __builtin_amdgcn_mfma_f32_16x16x32_bf16(ah, bh[n], acc[m][n], 0, 0, 0);
          acc[m][n] = __builtin_amdgcn_mfma_f32_16x16x32_bf16(ah, bl[n], acc[m][n], 0, 0, 0);
          acc[m][n] = __builtin_amdgcn_mfma_f32_16x16x32_bf16(al, bh[n], acc[m][n], 0, 0, 0);
        }
      }
      __builtin_amdgcn_s_setprio(0);
    }
  }

  // fused A-norms: thread's 8 staged float4s sit on fixed rows across all tiles
#pragma unroll
  for (int p = 0; p < 8; ++p) {
    int f2 = (p*512 + t) & 2047;
    int row = (f2 >> 7)*16 + ((f2 >> 1) & 15);
    atomicAdd(&ninSq[row], ssA[p]);
  }
  __syncthreads();
  if (t < 256) rnin[t] = 1.0f / fmaxf(sqrtf(ninSq[t]), 1e-12f);
  __syncthreads();

  // normalize + reduce upper diagonals (q = col - row >= 0)
#pragma unroll
  for (int n = 0; n < 4; ++n) {
    int col = wn*64 + n*16 + (lane & 15);
    float rc = rntg_s[col];
#pragma unroll
    for (int m = 0; m < 8; ++m) {
      f32x4 a = acc[m][n];
#pragma unroll
      for (int r = 0; r < 4; ++r) {
        int row = wm*128 + m*16 + (lane >> 4)*4 + r;
        int q = col - row;
        if (q >= 0) atomicAdd(&corrS[q], a[r] * rnin[row] * rc);
      }
    }
  }
  __syncthreads();

  // argmax over p (first max = smallest p wins) -> shift = q_best
  if (t < 256) {
    int q = 255 - t;
    float v = corrS[q] / (float)(256 - q);
    unsigned u = __float_as_uint(v);
    u = (u & 0x80000000u) ? ~u : (u | 0x80000000u);
    unsigned long long key = ((unsigned long long)u << 32) | (unsigned)q;
#pragma unroll
    for (int off = 32; off; off >>= 1) {
      unsigned long long o = __shfl_xor(key, off);
      if (o > key) key = o;
    }
    if ((t & 63) == 0) wkey[t >> 6] = key;
  }
  __syncthreads();
  if (t == 0) {
    unsigned long long k = wkey[0];
#pragma unroll
    for (int i = 1; i < 4; ++i) if (wkey[i] > k) k = wkey[i];
    shift_out[bs] = (int)(k & 0xFFFFFFFFull);
  }
}

// -------- shifted gather --------
__global__ void ct_gather(const float* __restrict__ input,
                          const int* __restrict__ shift,
                          float* __restrict__ out) {
  size_t idx = (size_t)blockIdx.x * blockDim.x + threadIdx.x;  // float4 units
  int w4 = (int)(idx & 63);
  int h  = (int)((idx >> 6) & 255);
  int sc = (int)(idx >> 14);
  int bs = sc / 3;
  int hh = h + shift[bs];
  float4 v = make_float4(0.f, 0.f, 0.f, 0.f);
  if (hh < H_) v = *(const float4*)(input + ((size_t)sc << 16) + (size_t)hh * W_ + w4*4);
  *(float4*)(out + (idx << 2)) = v;
}

extern "C" void kernel_launch(void* const* d_in, const int* in_sizes, int n_in,
                              void* d_out, int out_size, void* d_ws, size_t ws_size,
                              hipStream_t stream) {
  const float* input  = (const float*)d_in[0];
  const float* target = (const float*)d_in[1];
  float* out = (float*)d_out;

  float* rntg  = (float*)d_ws;                      // 2048 f
  int*   shift = (int*)(rntg + 2048);               // 256 i
  ushort* BhG  = (ushort*)(shift + 256);            // 8*24*8192 ushort = 3 MB
  ushort* BlG  = BhG + (size_t)B_ * NT_ * TILE_ELEMS;

  ct_ntg       <<<512, 256, 0, stream>>>(target, rntg);
  ct_bsplit    <<<B_ * NT_, 256, 0, stream>>>(target, BhG, BlG);
  ct_corr_mfma <<<B_ * S_, 512, 0, stream>>>(input, BhG, BlG, rntg, shift);
  ct_gather    <<<(B_*S_*C_*H_*W_/4) / 256, 256, 0, stream>>>(input, shift, out);
}